// Round 9
// baseline (328.838 us; speedup 1.0000x reference)
//
#include <hip/hip_runtime.h>
#include <hip/hip_bf16.h>
#include <stdint.h>

// Problem constants
#define B_    4
#define L_    2048
#define INK   256
#define HID   1024
#define NH    8
#define DH    128
#define OUTF  256

typedef __bf16 v8bf __attribute__((ext_vector_type(8)));
typedef float  v4f  __attribute__((ext_vector_type(4)));

#define MFMA(a,b,c) __builtin_amdgcn_mfma_f32_16x16x32_bf16((a),(b),(c),0,0,0)

__device__ __forceinline__ void gl_lds16(const void* gsrc, void* ldsbase) {
  __builtin_amdgcn_global_load_lds(
      (const __attribute__((address_space(1))) unsigned int*)(uintptr_t)gsrc,
      (__attribute__((address_space(3))) unsigned int*)(uint32_t)(uintptr_t)ldsbase,
      16, 0, 0);
}
__device__ __forceinline__ void barrier_lgkm() {
  asm volatile("s_waitcnt lgkmcnt(0)\n\ts_barrier" ::: "memory");
}

__device__ __forceinline__ unsigned short bfbits(float f) {
  __bf16 h = (__bf16)f;
  return __builtin_bit_cast(unsigned short, h);
}
__device__ __forceinline__ unsigned pack2(float a, float b) {
  return (unsigned)bfbits(a) | ((unsigned)bfbits(b) << 16);
}
__device__ __forceinline__ float bflo(unsigned u) {
  return __builtin_bit_cast(float, u << 16);
}
__device__ __forceinline__ float bfhi(unsigned u) {
  return __builtin_bit_cast(float, u & 0xFFFF0000u);
}

// ---------------------------------------------------------------------------
// fp32 -> bf16 bulk convert (KEY, QUERY, VALUE, W_w, Wv_w)
// ---------------------------------------------------------------------------
struct ConvArgs {
  const float* src[5];
  __bf16* dst[5];
  int n[5];
};
__global__ __launch_bounds__(256)
void convert_kernel(ConvArgs a) {
  const int r = blockIdx.y;
  const int i = (blockIdx.x * 256 + threadIdx.x) * 4;
  if (i >= a.n[r]) return;
  const float4 v = *(const float4*)(a.src[r] + i);
  uint2 w;
  w.x = pack2(v.x, v.y);
  w.y = pack2(v.z, v.w);
  *reinterpret_cast<uint2*>(a.dst[r] + i) = w;
}

// Wo[o][dd*8+h] fp32  ->  Wop[o][h*128+dd] bf16   (head-major permute)
__global__ __launch_bounds__(256)
void wo_perm_kernel(const float* __restrict__ Wo, __bf16* __restrict__ Wop) {
  const int o = blockIdx.x;
  const int hidp = threadIdx.x * 4;
  const int h = hidp >> 7, dd = hidp & 127;
  const float* src = Wo + (size_t)o * HID;
  const float v0 = src[(dd + 0) * 8 + h];
  const float v1 = src[(dd + 1) * 8 + h];
  const float v2 = src[(dd + 2) * 8 + h];
  const float v3 = src[(dd + 3) * 8 + h];
  uint2 w;
  w.x = pack2(v0, v1);
  w.y = pack2(v2, v3);
  *reinterpret_cast<uint2*>(Wop + (size_t)o * HID + hidp) = w;
}

// ---------------------------------------------------------------------------
// Projection (bf16 NT GEMM, K=256): out = (X W^T + bias) * scale
// Merged K/Q/V: blockIdx.z selects operand set. mode 0 (K,Q):
//   out[((b*8+h)*L+i)*128+dd]
// mode 1 (V, z==2): attention-tile layout, per (b,h) per 32-i tile 8KB block:
//   elem = (bh*64 + i>>5)*4096 + (ii*128 + dd)*8 + (i&7), ii=(i>>3)&3
// ---------------------------------------------------------------------------
struct ProjArgs {
  const __bf16* X[3];
  const __bf16* W[3];
  const float*  bias[3];
  float scale[3];
  __bf16* out[3];
};
__global__ __launch_bounds__(256, 2)
void proj_kernel(ProjArgs pa)
{
  __shared__ __bf16 sA[2][128 * 64];
  __shared__ __bf16 sB[2][128 * 64];
  const int z = blockIdx.z;
  const __bf16* X = pa.X[z];
  const __bf16* W = pa.W[z];
  const float* bias = pa.bias[z];
  const float scale = pa.scale[z];
  __bf16* out = pa.out[z];
  const int mode = (z == 2);

  const int tid  = threadIdx.x;
  const int lane = tid & 63;
  const int wid  = tid >> 6;
  const int l15  = lane & 15;
  const int q    = lane >> 4;
  const int mblk = blockIdx.x * 128;
  const int nblk = blockIdx.y * 128;

  v4f acc[4][4];
  const v4f vz = {0.f, 0.f, 0.f, 0.f};
#pragma unroll
  for (int i = 0; i < 4; i++)
#pragma unroll
    for (int j = 0; j < 4; j++) acc[i][j] = vz;

  const char* Ab = (const char*)X + (size_t)mblk * 512;
  const char* Bb = (const char*)W + (size_t)nblk * 512;

  auto stage = [&](int p, int c) {
    const int koff = c * 128;
#pragma unroll
    for (int j = 0; j < 4; j++) {
      const int slot = j * 256 + tid;
      const int row = slot >> 3, g = slot & 7;
      gl_lds16(Ab + (size_t)row * 512 + koff + ((g ^ (row & 7)) << 4),
               &sA[p][(j * 256 + wid * 64) * 8]);
    }
#pragma unroll
    for (int j = 0; j < 4; j++) {
      const int slot = j * 256 + tid;
      const int row = slot >> 3, g = slot & 7;
      gl_lds16(Bb + (size_t)row * 512 + koff + ((g ^ (row & 7)) << 4),
               &sB[p][(j * 256 + wid * 64) * 8]);
    }
  };

  stage(0, 0);
  __syncthreads();
#pragma unroll
  for (int c = 0; c < 4; c++) {
    const int p = c & 1;
    if (c + 1 < 4) stage(1 - p, c + 1);
#pragma unroll
    for (int s = 0; s < 2; s++) {
      v8bf a[4], b[4];
#pragma unroll
      for (int t = 0; t < 4; t++) {
        const int row = (wid & 1) * 64 + t * 16 + l15;
        a[t] = *(const v8bf*)&sA[p][(row << 6) + (((s * 4 + q) ^ (row & 7)) << 3)];
      }
#pragma unroll
      for (int t = 0; t < 4; t++) {
        const int row = (wid >> 1) * 64 + t * 16 + l15;
        b[t] = *(const v8bf*)&sB[p][(row << 6) + (((s * 4 + q) ^ (row & 7)) << 3)];
      }
#pragma unroll
      for (int tm = 0; tm < 4; tm++)
#pragma unroll
        for (int tn = 0; tn < 4; tn++)
          acc[tm][tn] = MFMA(a[tm], b[tn], acc[tm][tn]);
    }
    __syncthreads();
  }

#pragma unroll
  for (int tn = 0; tn < 4; tn++) {
    const int n = nblk + (wid >> 1) * 64 + tn * 16 + l15;
    const float bv = bias[n];
    const int h = n & 7;
    const int dd = n >> 3;
#pragma unroll
    for (int tm = 0; tm < 4; tm++)
#pragma unroll
      for (int r = 0; r < 4; r++) {
        const int m = mblk + (wid & 1) * 64 + tm * 16 + q * 4 + r;
        const int b = m >> 11;
        const int i = m & (L_ - 1);
        const float v = (acc[tm][tn][r] + bv) * scale;
        size_t idx;
        if (mode == 0) {
          idx = ((size_t)(b * NH + h) * L_ + i) * DH + dd;
        } else {
          const int ii = (i >> 3) & 3;
          idx = ((size_t)(b * NH + h) * 64 + (i >> 5)) * 4096 +
                (ii * 128 + dd) * 8 + (i & 7);
        }
        out[idx] = (__bf16)v;
      }
  }
}

// ---------------------------------------------------------------------------
// FUSED attention v7: 64-i barrier rounds (2 sub-tiles of 32 i each), halving
// barrier count vs v6 (16 rounds x 2 barriers). Block 512 thr = 8 waves
// (wave h = head h), k=64 cols, i-half per block. Grid (32, 2, 4) = 256.
// LDS: single 64KB exchange sPe [8h][64k rows of 128B][64i] bf16,
// 16B-granule swizzle ^(k&7), consistent across write/normalize/pb phases.
// Registers: qf 64 + ka 32 + va 32 (reused per sub-tile) ~ 128 VGPR,
// cacc 128 AGPR -> 256 total = 2 waves/SIMD (occupancy ceiling, see m69).
// Output: bf16 partials Hd0/Hd1 [b*L + k][h*128 + dd]; summed in outproj.
// ---------------------------------------------------------------------------
__global__ __launch_bounds__(512, 2)
void fused_attn_kernel(const __bf16* __restrict__ Kp,
                       const __bf16* __restrict__ Qp,
                       const __bf16* __restrict__ Vg,
                       __bf16* __restrict__ Hd0,
                       __bf16* __restrict__ Hd1)
{
  extern __shared__ char sPe[];   // 65536 B

  const int tid  = threadIdx.x;
  const int lane = tid & 63;
  const int h    = tid >> 6;          // wave id == head
  const int l15  = lane & 15;
  const int q    = lane >> 4;
  const int k0   = blockIdx.x * 64;
  const int ih   = blockIdx.y;
  const int b    = blockIdx.z;

  const char* KpH = (const char*)Kp + (size_t)(b * NH + h) * L_ * DH * 2;
  const char* QpH = (const char*)Qp + (size_t)(b * NH + h) * L_ * DH * 2;
  const char* VgH = (const char*)Vg + (size_t)(b * NH + h) * 64 * 8192;
  char* sPh = sPe + h * 8192;
  __bf16* Hd = ih ? Hd1 : Hd0;

  // Q fragments for 64 k-cols: qf[ks][n][c] (64 VGPRs, persistent)
  v8bf qf[2][2][4];
#pragma unroll
  for (int ks = 0; ks < 2; ks++)
#pragma unroll
    for (int n = 0; n < 2; n++)
#pragma unroll
      for (int c = 0; c < 4; c++)
        qf[ks][n][c] = *(const v8bf*)(QpH +
            (size_t)(k0 + ks * 32 + n * 16 + l15) * 256 + c * 64 + q * 16);

  v4f cacc[8][4];
  const v4f vz = {0.f, 0.f, 0.f, 0.f};
#pragma unroll
  for (int t = 0; t < 8; t++)
#pragma unroll
    for (int n = 0; n < 4; n++) cacc[t][n] = vz;

  const int it0 = ih * 32;
#pragma unroll 1
  for (int r = 0; r < 16; ++r) {
    // ======== score phase: two 32-i sub-tiles ========
#pragma unroll
    for (int sub = 0; sub < 2; ++sub) {
      const int it = it0 + r * 2 + sub;
      v8bf ka[2][4];
      {
        const char* base = KpH + (size_t)it * 32 * 256;
#pragma unroll
        for (int si = 0; si < 2; si++)
#pragma unroll
          for (int c = 0; c < 4; c++)
            ka[si][c] = *(const v8bf*)(base + (si * 16 + l15) * 256 + (c * 4 + q) * 16);
      }
#pragma unroll
      for (int ks = 0; ks < 2; ks++) {
        v4f s[2][2];
#pragma unroll
        for (int si = 0; si < 2; si++)
#pragma unroll
          for (int n = 0; n < 2; n++) s[si][n] = vz;
#pragma unroll
        for (int c = 0; c < 4; c++)
#pragma unroll
          for (int si = 0; si < 2; si++)
#pragma unroll
            for (int n = 0; n < 2; n++)
              s[si][n] = MFMA(ka[si][c], qf[ks][n][c], s[si][n]);
        // exp (Q pre-scaled by log2e/sqrt(128)) + swizzled write
#pragma unroll
        for (int si = 0; si < 2; si++)
#pragma unroll
          for (int n = 0; n < 2; n++) {
            const int kb = ks * 32 + n * 16 + l15;
            const int pg = (sub * 4 + si * 2 + (q >> 1)) ^ (kb & 7);
            uint2 w;
            w.x = pack2(exp2f(s[si][n][0]), exp2f(s[si][n][1]));
            w.y = pack2(exp2f(s[si][n][2]), exp2f(s[si][n][3]));
            *(uint2*)(sPh + kb * 128 + pg * 16 + (q & 1) * 8) = w;
          }
      }
    }
    barrier_lgkm();

    // ======== normalize: thread owns (kk=tid>>3, phys granule tid&7) ========
    {
      const int off = (tid >> 3) * 128 + (tid & 7) * 16;
      uint4 u[8];
      float s0 = 0.f, s1 = 0.f, s2 = 0.f, s3 = 0.f;
      float s4 = 0.f, s5 = 0.f, s6 = 0.f, s7 = 0.f;
#pragma unroll
      for (int hh = 0; hh < 8; hh++) {
        u[hh] = *(const uint4*)(sPe + hh * 8192 + off);
        s0 += bflo(u[hh].x); s1 += bfhi(u[hh].x);
        s2 += bflo(u[hh].y); s3 += bfhi(u[hh].y);
        s4 += bflo(u[hh].z); s5 += bfhi(u[hh].z);
        s6 += bflo(u[hh].w); s7 += bfhi(u[hh].w);
      }
      const float r0 = __builtin_amdgcn_rcpf(s0);
      const float r1 = __builtin_amdgcn_rcpf(s1);
      const float r2 = __builtin_amdgcn_rcpf(s2);
      const float r3 = __builtin_amdgcn_rcpf(s3);
      const float r4 = __builtin_amdgcn_rcpf(s4);
      const float r5 = __builtin_amdgcn_rcpf(s5);
      const float r6 = __builtin_amdgcn_rcpf(s6);
      const float r7 = __builtin_amdgcn_rcpf(s7);
#pragma unroll
      for (int hh = 0; hh < 8; hh++) {
        uint4 w;
        w.x = pack2(bflo(u[hh].x) * r0, bfhi(u[hh].x) * r1);
        w.y = pack2(bflo(u[hh].y) * r2, bfhi(u[hh].y) * r3);
        w.z = pack2(bflo(u[hh].z) * r4, bfhi(u[hh].z) * r5);
        w.w = pack2(bflo(u[hh].w) * r6, bfhi(u[hh].w) * r7);
        *(uint4*)(sPe + hh * 8192 + off) = w;
      }
    }
    barrier_lgkm();

    // ======== PV phase: two 32-i sub-tiles ========
#pragma unroll
    for (int sub = 0; sub < 2; ++sub) {
      const int it = it0 + r * 2 + sub;
      v8bf va[8];
      {
        const char* base = VgH + (size_t)it * 8192 + q * 2048;
#pragma unroll
        for (int t = 0; t < 8; t++)
          va[t] = *(const v8bf*)(base + (t * 16 + l15) * 16);
      }
      v8bf pb[4];
#pragma unroll
      for (int n = 0; n < 4; n++) {
        const int kb = n * 16 + l15;
        const int pg = (sub * 4 + q) ^ (kb & 7);
        pb[n] = *(const v8bf*)(sPh + kb * 128 + pg * 16);
      }
#pragma unroll
      for (int t = 0; t < 8; t++)
#pragma unroll
        for (int n = 0; n < 4; n++)
          cacc[t][n] = MFMA(va[t], pb[n], cacc[t][n]);
    }
  }

  // ---- epilogue: C[dd=128][k=64] -> Hd[b*L + k][h*128 + dd] ----
#pragma unroll
  for (int t = 0; t < 8; t++)
#pragma unroll
    for (int n = 0; n < 4; n++) {
      uint2 w;
      w.x = pack2(cacc[t][n][0], cacc[t][n][1]);
      w.y = pack2(cacc[t][n][2], cacc[t][n][3]);
      char* dst = (char*)Hd +
          (((size_t)(b * L_ + k0 + n * 16 + l15)) * HID + h * DH + t * 16 + q * 4) * 2;
      *(uint2*)dst = w;
    }
}

// ---------------------------------------------------------------------------
// Output projection with partial-sum fold:
//   out[m][o] = sum_k (Hd0[m][k]+Hd1[m][k]) * Wop[o][k] + bo[o]
// ---------------------------------------------------------------------------
__device__ __forceinline__ v8bf add8(v8bf a, v8bf b) {
  v8bf r;
#pragma unroll
  for (int i = 0; i < 8; i++) r[i] = (__bf16)((float)a[i] + (float)b[i]);
  return r;
}

__global__ __launch_bounds__(256, 2)
void outproj_kernel(const __bf16* __restrict__ Hd0, const __bf16* __restrict__ Hd1,
                    const __bf16* __restrict__ Wop,
                    const float* __restrict__ bo, float* __restrict__ out)
{
  __shared__ __bf16 sA0[2][64 * 64];
  __shared__ __bf16 sA1[2][64 * 64];
  __shared__ __bf16 sB [2][64 * 64];
  const int tid  = threadIdx.x;
  const int lane = tid & 63;
  const int wid  = tid >> 6;
  const int l15  = lane & 15;
  const int q    = lane >> 4;
  const int mblk = blockIdx.x * 64;
  const int nblk = blockIdx.y * 64;

  const char* A0b = (const char*)Hd0 + (size_t)mblk * 2048;
  const char* A1b = (const char*)Hd1 + (size_t)mblk * 2048;
  const char* Bb  = (const char*)Wop + (size_t)nblk * 2048;

  auto stage = [&](int p, int c) {
#pragma unroll
    for (int j = 0; j < 2; j++) {
      const int slot = j * 256 + tid;
      const int row = slot >> 3, g = slot & 7;
      const size_t goff = (size_t)row * 2048 + c * 128 + ((g ^ (row & 7)) << 4);
      gl_lds16(A0b + goff, &sA0[p][(j * 256 + wid * 64) * 8]);
      gl_lds16(A1b + goff, &sA1[p][(j * 256 + wid * 64) * 8]);
      gl_lds16(Bb  + goff, &sB [p][(j * 256 + wid * 64) * 8]);
    }
  };

  v4f acc[2][2];
  const v4f vz = {0.f, 0.f, 0.f, 0.f};
#pragma unroll
  for (int i = 0; i < 2; i++)
#pragma unroll
    for (int j = 0; j < 2; j++) acc[i][j] = vz;

  stage(0, 0);
  __syncthreads();
#pragma unroll 1
  for (int c = 0; c < 16; c++) {
    const int p = c & 1;
    if (c + 1 < 16) stage(1 - p, c + 1);
#pragma unroll
    for (int s = 0; s < 2; s++) {
      v8bf a[2], bb[2];
#pragma unroll
      for (int t = 0; t < 2; t++) {
        const int row = (wid & 1) * 32 + t * 16 + l15;
        const int off = (row << 6) + (((s * 4 + q) ^ (row & 7)) << 3);
        a[t] = add8(*(const v8bf*)&sA0[p][off], *(const v8bf*)&sA1[p][off]);
      }
#pragma unroll
      for (int t = 0; t < 2; t++) {
        const int row = (wid >> 1) * 32 + t * 16 + l15;
        bb[t] = *(const v8bf*)&sB[p][(row << 6) + (((s * 4 + q) ^ (row & 7)) << 3)];
      }
#pragma unroll
      for (int tm = 0; tm < 2; tm++)
#pragma unroll
        for (int tn = 0; tn < 2; tn++)
          acc[tm][tn] = MFMA(a[tm], bb[tn], acc[tm][tn]);
    }
    __syncthreads();
  }

#pragma unroll
  for (int tn = 0; tn < 2; tn++) {
    const int n = nblk + (wid >> 1) * 32 + tn * 16 + l15;
    const float bv = bo[n];
#pragma unroll
    for (int tm = 0; tm < 2; tm++)
#pragma unroll
      for (int r = 0; r < 4; r++) {
        const int m = mblk + (wid & 1) * 32 + tm * 16 + q * 4 + r;
        out[(size_t)m * OUTF + n] = acc[tm][tn][r] + bv;
      }
  }
}

// ---------------------------------------------------------------------------
// Workspace layout (bytes):
//   0      Kp   16 MiB  [B*NH][L][DH] bf16
//   16 MiB Qp   16 MiB  (pre-scaled by log2e/sqrt(128))
//   32 MiB Vg   16 MiB  [B*NH][64 tiles][8KB attention-tile layout]
//   48 MiB Hd0  16 MiB  partial (i 0..1023)   [conv area inside, dead by then]
//   64 MiB Hd1  16 MiB  partial (i 1024..2047)
//   80 MiB Wop  512 KiB [O][h*128+dd] bf16
// ---------------------------------------------------------------------------
extern "C" void kernel_launch(void* const* d_in, const int* in_sizes, int n_in,
                              void* d_out, int out_size, void* d_ws, size_t ws_size,
                              hipStream_t stream) {
  const float* KEY   = (const float*)d_in[0];
  const float* VALUE = (const float*)d_in[1];
  const float* QUERY = (const float*)d_in[2];
  const float* W_w   = (const float*)d_in[3];
  const float* W_b   = (const float*)d_in[4];
  const float* Wv_w  = (const float*)d_in[5];
  const float* Wv_b  = (const float*)d_in[6];
  const float* Wo_w  = (const float*)d_in[7];
  const float* Wo_b  = (const float*)d_in[8];
  float* out = (float*)d_out;

  const size_t MB = 1024 * 1024;
  char* ws = (char*)d_ws;
  __bf16* Kp  = (__bf16*)(ws);
  __bf16* Qp  = (__bf16*)(ws + 16 * MB);
  __bf16* Vg  = (__bf16*)(ws + 32 * MB);
  __bf16* Hd0 = (__bf16*)(ws + 48 * MB);
  __bf16* Hd1 = (__bf16*)(ws + 64 * MB);
  __bf16* Wop = (__bf16*)(ws + 80 * MB);
  // conversion area inside Hd0 region (dead before fused_attn writes Hd0)
  __bf16* Xk  = (__bf16*)(ws + 48 * MB);
  __bf16* Xq  = (__bf16*)(ws + 48 * MB + 4 * MB);
  __bf16* Xv  = (__bf16*)(ws + 48 * MB + 8 * MB);
  __bf16* Wb  = (__bf16*)(ws + 48 * MB + 12 * MB);
  __bf16* Wvb = (__bf16*)(ws + 48 * MB + 12 * MB + 512 * 1024);

  ConvArgs ca;
  ca.src[0] = KEY;   ca.dst[0] = Xk;  ca.n[0] = B_ * L_ * INK;
  ca.src[1] = QUERY; ca.dst[1] = Xq;  ca.n[1] = B_ * L_ * INK;
  ca.src[2] = VALUE; ca.dst[2] = Xv;  ca.n[2] = B_ * L_ * INK;
  ca.src[3] = W_w;   ca.dst[3] = Wb;  ca.n[3] = HID * INK;
  ca.src[4] = Wv_w;  ca.dst[4] = Wvb; ca.n[4] = HID * INK;
  convert_kernel<<<dim3(2048, 5), 256, 0, stream>>>(ca);
  wo_perm_kernel<<<dim3(256), 256, 0, stream>>>(Wo_w, Wop);

  const float c2 = 0.12751744f;  // log2(e)/sqrt(128)
  ProjArgs pa;
  pa.X[0] = Xk;  pa.W[0] = Wb;  pa.bias[0] = W_b;  pa.scale[0] = 1.0f; pa.out[0] = Kp;
  pa.X[1] = Xq;  pa.W[1] = Wb;  pa.bias[1] = W_b;  pa.scale[1] = c2;   pa.out[1] = Qp;
  pa.X[2] = Xv;  pa.W[2] = Wvb; pa.bias[2] = Wv_b; pa.scale[2] = 1.0f; pa.out[2] = Vg;
  proj_kernel<<<dim3(64, 8, 3), 256, 0, stream>>>(pa);

  fused_attn_kernel<<<dim3(32, 2, B_), 512, 65536, stream>>>(Kp, Qp, Vg, Hd0, Hd1);

  outproj_kernel<<<dim3(128, 4), 256, 0, stream>>>(Hd0, Hd1, Wop, Wo_b, out);
}

// Round 10
// 308.399 us; speedup vs baseline: 1.0663x; 1.0663x over previous
//
#include <hip/hip_runtime.h>
#include <hip/hip_bf16.h>
#include <stdint.h>

// Problem constants
#define B_    4
#define L_    2048
#define INK   256
#define HID   1024
#define NH    8
#define DH    128
#define OUTF  256

typedef __bf16 v8bf __attribute__((ext_vector_type(8)));
typedef float  v4f  __attribute__((ext_vector_type(4)));

#define MFMA(a,b,c) __builtin_amdgcn_mfma_f32_16x16x32_bf16((a),(b),(c),0,0,0)

__device__ __forceinline__ void gl_lds16(const void* gsrc, void* ldsbase) {
  __builtin_amdgcn_global_load_lds(
      (const __attribute__((address_space(1))) unsigned int*)(uintptr_t)gsrc,
      (__attribute__((address_space(3))) unsigned int*)(uint32_t)(uintptr_t)ldsbase,
      16, 0, 0);
}
__device__ __forceinline__ void barrier_lgkm() {
  asm volatile("s_waitcnt lgkmcnt(0)\n\ts_barrier" ::: "memory");
}

__device__ __forceinline__ unsigned short bfbits(float f) {
  __bf16 h = (__bf16)f;
  return __builtin_bit_cast(unsigned short, h);
}
__device__ __forceinline__ unsigned pack2(float a, float b) {
  return (unsigned)bfbits(a) | ((unsigned)bfbits(b) << 16);
}
__device__ __forceinline__ float bflo(unsigned u) {
  return __builtin_bit_cast(float, u << 16);
}
__device__ __forceinline__ float bfhi(unsigned u) {
  return __builtin_bit_cast(float, u & 0xFFFF0000u);
}

// ---------------------------------------------------------------------------
// fp32 -> bf16 bulk convert (KEY, QUERY, VALUE, W_w, Wv_w), plus (y==5)
// Wo[o][dd*8+h] fp32 -> Wop[o][h*128+dd] bf16 head-major permute.
// ---------------------------------------------------------------------------
struct ConvArgs {
  const float* src[5];
  __bf16* dst[5];
  int n[5];
  const float* Wo;
  __bf16* Wop;
};
__global__ __launch_bounds__(256)
void convert_kernel(ConvArgs a) {
  const int r = blockIdx.y;
  if (r == 5) {
    const int o = blockIdx.x;
    if (o >= OUTF) return;
    const int hidp = threadIdx.x * 4;
    const int h = hidp >> 7, dd = hidp & 127;
    const float* src = a.Wo + (size_t)o * HID;
    uint2 w;
    w.x = pack2(src[(dd + 0) * 8 + h], src[(dd + 1) * 8 + h]);
    w.y = pack2(src[(dd + 2) * 8 + h], src[(dd + 3) * 8 + h]);
    *reinterpret_cast<uint2*>(a.Wop + (size_t)o * HID + hidp) = w;
    return;
  }
  const int i = (blockIdx.x * 256 + threadIdx.x) * 4;
  if (i >= a.n[r]) return;
  const float4 v = *(const float4*)(a.src[r] + i);
  uint2 w;
  w.x = pack2(v.x, v.y);
  w.y = pack2(v.z, v.w);
  *reinterpret_cast<uint2*>(a.dst[r] + i) = w;
}

// ---------------------------------------------------------------------------
// Projection (bf16 NT GEMM, K=256): out = (X W^T + bias) * scale
// Merged K/Q/V: blockIdx.z selects operand set. mode 0 (K,Q):
//   out[((b*8+h)*L+i)*128+dd]
// mode 1 (V, z==2): attention-tile layout, per (b,h) per 32-i tile 8KB block:
//   elem = (bh*64 + i>>5)*4096 + (ii*128 + dd)*8 + (i&7), ii=(i>>3)&3
// ---------------------------------------------------------------------------
struct ProjArgs {
  const __bf16* X[3];
  const __bf16* W[3];
  const float*  bias[3];
  float scale[3];
  __bf16* out[3];
};
__global__ __launch_bounds__(256, 2)
void proj_kernel(ProjArgs pa)
{
  __shared__ __bf16 sA[2][128 * 64];
  __shared__ __bf16 sB[2][128 * 64];
  const int z = blockIdx.z;
  const __bf16* X = pa.X[z];
  const __bf16* W = pa.W[z];
  const float* bias = pa.bias[z];
  const float scale = pa.scale[z];
  __bf16* out = pa.out[z];
  const int mode = (z == 2);

  const int tid  = threadIdx.x;
  const int lane = tid & 63;
  const int wid  = tid >> 6;
  const int l15  = lane & 15;
  const int q    = lane >> 4;
  const int mblk = blockIdx.x * 128;
  const int nblk = blockIdx.y * 128;

  v4f acc[4][4];
  const v4f vz = {0.f, 0.f, 0.f, 0.f};
#pragma unroll
  for (int i = 0; i < 4; i++)
#pragma unroll
    for (int j = 0; j < 4; j++) acc[i][j] = vz;

  const char* Ab = (const char*)X + (size_t)mblk * 512;
  const char* Bb = (const char*)W + (size_t)nblk * 512;

  auto stage = [&](int p, int c) {
    const int koff = c * 128;
#pragma unroll
    for (int j = 0; j < 4; j++) {
      const int slot = j * 256 + tid;
      const int row = slot >> 3, g = slot & 7;
      gl_lds16(Ab + (size_t)row * 512 + koff + ((g ^ (row & 7)) << 4),
               &sA[p][(j * 256 + wid * 64) * 8]);
    }
#pragma unroll
    for (int j = 0; j < 4; j++) {
      const int slot = j * 256 + tid;
      const int row = slot >> 3, g = slot & 7;
      gl_lds16(Bb + (size_t)row * 512 + koff + ((g ^ (row & 7)) << 4),
               &sB[p][(j * 256 + wid * 64) * 8]);
    }
  };

  stage(0, 0);
  __syncthreads();
#pragma unroll
  for (int c = 0; c < 4; c++) {
    const int p = c & 1;
    if (c + 1 < 4) stage(1 - p, c + 1);
#pragma unroll
    for (int s = 0; s < 2; s++) {
      v8bf a[4], b[4];
#pragma unroll
      for (int t = 0; t < 4; t++) {
        const int row = (wid & 1) * 64 + t * 16 + l15;
        a[t] = *(const v8bf*)&sA[p][(row << 6) + (((s * 4 + q) ^ (row & 7)) << 3)];
      }
#pragma unroll
      for (int t = 0; t < 4; t++) {
        const int row = (wid >> 1) * 64 + t * 16 + l15;
        b[t] = *(const v8bf*)&sB[p][(row << 6) + (((s * 4 + q) ^ (row & 7)) << 3)];
      }
#pragma unroll
      for (int tm = 0; tm < 4; tm++)
#pragma unroll
        for (int tn = 0; tn < 4; tn++)
          acc[tm][tn] = MFMA(a[tm], b[tn], acc[tm][tn]);
    }
    __syncthreads();
  }

#pragma unroll
  for (int tn = 0; tn < 4; tn++) {
    const int n = nblk + (wid >> 1) * 64 + tn * 16 + l15;
    const float bv = bias[n];
    const int h = n & 7;
    const int dd = n >> 3;
#pragma unroll
    for (int tm = 0; tm < 4; tm++)
#pragma unroll
      for (int r = 0; r < 4; r++) {
        const int m = mblk + (wid & 1) * 64 + tm * 16 + q * 4 + r;
        const int b = m >> 11;
        const int i = m & (L_ - 1);
        const float v = (acc[tm][tn][r] + bv) * scale;
        size_t idx;
        if (mode == 0) {
          idx = ((size_t)(b * NH + h) * L_ + i) * DH + dd;
        } else {
          const int ii = (i >> 3) & 3;
          idx = ((size_t)(b * NH + h) * 64 + (i >> 5)) * 4096 +
                (ii * 128 + dd) * 8 + (i & 7);
        }
        out[idx] = (__bf16)v;
      }
  }
}

// ---------------------------------------------------------------------------
// FUSED attention v8 = v6 (R8 core, best known) + XCD-aware swizzle.
// Block 512 thr = 8 waves (wave h = head h), k=64 cols, i-half per block.
// 1D grid of 256: lin = j*8 + g, g = (b,ih) sharing-group -> dispatch
// round-robin puts all 32 blocks sharing one 4MB K+V working set on the
// same XCD (one XCD L2 = 4 MiB). Decode: g = lin&7, j = lin>>3.
// LDS: 32KB in-place exchange sPe [8h][64k][32i] bf16, swizzle gi^(k&6).
// Per round: ka -> score (2 k-halves) -> exp+write -> barrier -> va loads +
// in-place 8-head normalize -> barrier -> pb + PV.
// Output: bf16 partials Hd0/Hd1 [b*L + k][h*128 + dd]; summed in outproj.
// ---------------------------------------------------------------------------
__global__ __launch_bounds__(512, 2)
void fused_attn_kernel(const __bf16* __restrict__ Kp,
                       const __bf16* __restrict__ Qp,
                       const __bf16* __restrict__ Vg,
                       __bf16* __restrict__ Hd0,
                       __bf16* __restrict__ Hd1)
{
  __shared__ char sPe[32768];

  const int tid  = threadIdx.x;
  const int lane = tid & 63;
  const int h    = tid >> 6;          // wave id == head
  const int l15  = lane & 15;
  const int q    = lane >> 4;
  const int g    = blockIdx.x & 7;    // sharing group -> XCD
  const int j    = blockIdx.x >> 3;   // k-tile within group
  const int b    = g >> 1;
  const int ih   = g & 1;
  const int k0   = j * 64;

  const char* KpH = (const char*)Kp + (size_t)(b * NH + h) * L_ * DH * 2;
  const char* QpH = (const char*)Qp + (size_t)(b * NH + h) * L_ * DH * 2;
  const char* VgH = (const char*)Vg + (size_t)(b * NH + h) * 64 * 8192;
  char* sPh = sPe + h * 4096;
  __bf16* Hd = ih ? Hd1 : Hd0;

  // Q fragments for 64 k-cols: qf[ks][n][c] (64 VGPRs, persistent)
  v8bf qf[2][2][4];
#pragma unroll
  for (int ks = 0; ks < 2; ks++)
#pragma unroll
    for (int n = 0; n < 2; n++)
#pragma unroll
      for (int c = 0; c < 4; c++)
        qf[ks][n][c] = *(const v8bf*)(QpH +
            (size_t)(k0 + ks * 32 + n * 16 + l15) * 256 + c * 64 + q * 16);

  v4f cacc[8][4];
  const v4f vz = {0.f, 0.f, 0.f, 0.f};
#pragma unroll
  for (int t = 0; t < 8; t++)
#pragma unroll
    for (int n = 0; n < 4; n++) cacc[t][n] = vz;

  const int it0 = ih * 32;
#pragma unroll 1
  for (int itl = 0; itl < 32; ++itl) {
    const int it = it0 + itl;

    // ---- K fragments (direct, coalesced 64B-line reads) ----
    v8bf ka[2][4];
    {
      const char* base = KpH + (size_t)it * 32 * 256;
#pragma unroll
      for (int si = 0; si < 2; si++)
#pragma unroll
        for (int c = 0; c < 4; c++)
          ka[si][c] = *(const v8bf*)(base + (si * 16 + l15) * 256 + (c * 4 + q) * 16);
    }

    // ---- score, one k-half at a time (keeps s at 16 regs) ----
#pragma unroll
    for (int ks = 0; ks < 2; ks++) {
      v4f s[2][2];
#pragma unroll
      for (int si = 0; si < 2; si++)
#pragma unroll
        for (int n = 0; n < 2; n++) s[si][n] = vz;
#pragma unroll
      for (int c = 0; c < 4; c++)
#pragma unroll
        for (int si = 0; si < 2; si++)
#pragma unroll
          for (int n = 0; n < 2; n++)
            s[si][n] = MFMA(ka[si][c], qf[ks][n][c], s[si][n]);
      // exp (Q pre-scaled by log2e/sqrt(128)) + swizzled write
#pragma unroll
      for (int si = 0; si < 2; si++)
#pragma unroll
        for (int n = 0; n < 2; n++) {
          const int kb = ks * 32 + n * 16 + l15;
          const int gi = si * 4 + q;
          uint2 w;
          w.x = pack2(exp2f(s[si][n][0]), exp2f(s[si][n][1]));
          w.y = pack2(exp2f(s[si][n][2]), exp2f(s[si][n][3]));
          *(uint2*)(sPh + kb * 64 + ((gi ^ (kb & 6)) << 3)) = w;
        }
    }
    barrier_lgkm();

    // ---- V fragments (pre-tiled, A-order): issue now, consumed in PV ----
    v8bf va[8];
    {
      const char* base = VgH + (size_t)it * 8192 + q * 2048;
#pragma unroll
      for (int t = 0; t < 8; t++)
        va[t] = *(const v8bf*)(base + (t * 16 + l15) * 16);
    }

    // ---- in-place 8-head normalize: thread owns (kk, i4*4..+3) ----
    {
      const int kk = tid >> 3;
      const int i4 = tid & 7;
      const int off = kk * 64 + ((i4 ^ (kk & 6)) << 3);
      uint2 u[8];
      float s0 = 0.f, s1 = 0.f, s2 = 0.f, s3 = 0.f;
#pragma unroll
      for (int hh = 0; hh < 8; hh++) {
        u[hh] = *(const uint2*)(sPe + hh * 4096 + off);
        s0 += bflo(u[hh].x);
        s1 += bfhi(u[hh].x);
        s2 += bflo(u[hh].y);
        s3 += bfhi(u[hh].y);
      }
      const float r0 = __builtin_amdgcn_rcpf(s0);
      const float r1 = __builtin_amdgcn_rcpf(s1);
      const float r2 = __builtin_amdgcn_rcpf(s2);
      const float r3 = __builtin_amdgcn_rcpf(s3);
#pragma unroll
      for (int hh = 0; hh < 8; hh++) {
        uint2 w;
        w.x = pack2(bflo(u[hh].x) * r0, bfhi(u[hh].x) * r1);
        w.y = pack2(bflo(u[hh].y) * r2, bfhi(u[hh].y) * r3);
        *(uint2*)(sPe + hh * 4096 + off) = w;
      }
    }
    barrier_lgkm();

    // ---- PV: pb (swizzle-consistent b128 reads) + 32 MFMAs ----
    v8bf pb[4];
#pragma unroll
    for (int n = 0; n < 4; n++) {
      const int kb = n * 16 + l15;
      pb[n] = *(const v8bf*)(sPh + kb * 64 + (((q * 2) ^ (kb & 6)) << 3));
    }
#pragma unroll
    for (int t = 0; t < 8; t++)
#pragma unroll
      for (int n = 0; n < 4; n++)
        cacc[t][n] = MFMA(va[t], pb[n], cacc[t][n]);
  }

  // ---- epilogue: C[dd=128][k=64] -> Hd[b*L + k][h*128 + dd] ----
#pragma unroll
  for (int t = 0; t < 8; t++)
#pragma unroll
    for (int n = 0; n < 4; n++) {
      uint2 w;
      w.x = pack2(cacc[t][n][0], cacc[t][n][1]);
      w.y = pack2(cacc[t][n][2], cacc[t][n][3]);
      char* dst = (char*)Hd +
          (((size_t)(b * L_ + k0 + n * 16 + l15)) * HID + h * DH + t * 16 + q * 4) * 2;
      *(uint2*)dst = w;
    }
}

// ---------------------------------------------------------------------------
// Output projection with partial-sum fold:
//   out[m][o] = sum_k (Hd0[m][k]+Hd1[m][k]) * Wop[o][k] + bo[o]
// ---------------------------------------------------------------------------
__device__ __forceinline__ v8bf add8(v8bf a, v8bf b) {
  v8bf r;
#pragma unroll
  for (int i = 0; i < 8; i++) r[i] = (__bf16)((float)a[i] + (float)b[i]);
  return r;
}

__global__ __launch_bounds__(256, 2)
void outproj_kernel(const __bf16* __restrict__ Hd0, const __bf16* __restrict__ Hd1,
                    const __bf16* __restrict__ Wop,
                    const float* __restrict__ bo, float* __restrict__ out)
{
  __shared__ __bf16 sA0[2][64 * 64];
  __shared__ __bf16 sA1[2][64 * 64];
  __shared__ __bf16 sB [2][64 * 64];
  const int tid  = threadIdx.x;
  const int lane = tid & 63;
  const int wid  = tid >> 6;
  const int l15  = lane & 15;
  const int q    = lane >> 4;
  const int mblk = blockIdx.x * 64;
  const int nblk = blockIdx.y * 64;

  const char* A0b = (const char*)Hd0 + (size_t)mblk * 2048;
  const char* A1b = (const char*)Hd1 + (size_t)mblk * 2048;
  const char* Bb  = (const char*)Wop + (size_t)nblk * 2048;

  auto stage = [&](int p, int c) {
#pragma unroll
    for (int j = 0; j < 2; j++) {
      const int slot = j * 256 + tid;
      const int row = slot >> 3, g = slot & 7;
      const size_t goff = (size_t)row * 2048 + c * 128 + ((g ^ (row & 7)) << 4);
      gl_lds16(A0b + goff, &sA0[p][(j * 256 + wid * 64) * 8]);
      gl_lds16(A1b + goff, &sA1[p][(j * 256 + wid * 64) * 8]);
      gl_lds16(Bb  + goff, &sB [p][(j * 256 + wid * 64) * 8]);
    }
  };

  v4f acc[2][2];
  const v4f vz = {0.f, 0.f, 0.f, 0.f};
#pragma unroll
  for (int i = 0; i < 2; i++)
#pragma unroll
    for (int j = 0; j < 2; j++) acc[i][j] = vz;

  stage(0, 0);
  __syncthreads();
#pragma unroll 1
  for (int c = 0; c < 16; c++) {
    const int p = c & 1;
    if (c + 1 < 16) stage(1 - p, c + 1);
#pragma unroll
    for (int s = 0; s < 2; s++) {
      v8bf a[2], bb[2];
#pragma unroll
      for (int t = 0; t < 2; t++) {
        const int row = (wid & 1) * 32 + t * 16 + l15;
        const int off = (row << 6) + (((s * 4 + q) ^ (row & 7)) << 3);
        a[t] = add8(*(const v8bf*)&sA0[p][off], *(const v8bf*)&sA1[p][off]);
      }
#pragma unroll
      for (int t = 0; t < 2; t++) {
        const int row = (wid >> 1) * 32 + t * 16 + l15;
        bb[t] = *(const v8bf*)&sB[p][(row << 6) + (((s * 4 + q) ^ (row & 7)) << 3)];
      }
#pragma unroll
      for (int tm = 0; tm < 2; tm++)
#pragma unroll
        for (int tn = 0; tn < 2; tn++)
          acc[tm][tn] = MFMA(a[tm], bb[tn], acc[tm][tn]);
    }
    __syncthreads();
  }

#pragma unroll
  for (int tn = 0; tn < 2; tn++) {
    const int n = nblk + (wid >> 1) * 32 + tn * 16 + l15;
    const float bv = bo[n];
#pragma unroll
    for (int tm = 0; tm < 2; tm++)
#pragma unroll
      for (int r = 0; r < 4; r++) {
        const int m = mblk + (wid & 1) * 32 + tm * 16 + q * 4 + r;
        out[(size_t)m * OUTF + n] = acc[tm][tn][r] + bv;
      }
  }
}

// ---------------------------------------------------------------------------
// Workspace layout (bytes):
//   0      Kp   16 MiB  [B*NH][L][DH] bf16
//   16 MiB Qp   16 MiB  (pre-scaled by log2e/sqrt(128))
//   32 MiB Vg   16 MiB  [B*NH][64 tiles][8KB attention-tile layout]
//   48 MiB Hd0  16 MiB  partial (i 0..1023)   [conv area inside, dead by then]
//   64 MiB Hd1  16 MiB  partial (i 1024..2047)
//   80 MiB Wop  512 KiB [O][h*128+dd] bf16
// ---------------------------------------------------------------------------
extern "C" void kernel_launch(void* const* d_in, const int* in_sizes, int n_in,
                              void* d_out, int out_size, void* d_ws, size_t ws_size,
                              hipStream_t stream) {
  const float* KEY   = (const float*)d_in[0];
  const float* VALUE = (const float*)d_in[1];
  const float* QUERY = (const float*)d_in[2];
  const float* W_w   = (const float*)d_in[3];
  const float* W_b   = (const float*)d_in[4];
  const float* Wv_w  = (const float*)d_in[5];
  const float* Wv_b  = (const float*)d_in[6];
  const float* Wo_w  = (const float*)d_in[7];
  const float* Wo_b  = (const float*)d_in[8];
  float* out = (float*)d_out;

  const size_t MB = 1024 * 1024;
  char* ws = (char*)d_ws;
  __bf16* Kp  = (__bf16*)(ws);
  __bf16* Qp  = (__bf16*)(ws + 16 * MB);
  __bf16* Vg  = (__bf16*)(ws + 32 * MB);
  __bf16* Hd0 = (__bf16*)(ws + 48 * MB);
  __bf16* Hd1 = (__bf16*)(ws + 64 * MB);
  __bf16* Wop = (__bf16*)(ws + 80 * MB);
  // conversion area inside Hd0 region (dead before fused_attn writes Hd0)
  __bf16* Xk  = (__bf16*)(ws + 48 * MB);
  __bf16* Xq  = (__bf16*)(ws + 48 * MB + 4 * MB);
  __bf16* Xv  = (__bf16*)(ws + 48 * MB + 8 * MB);
  __bf16* Wb  = (__bf16*)(ws + 48 * MB + 12 * MB);
  __bf16* Wvb = (__bf16*)(ws + 48 * MB + 12 * MB + 512 * 1024);

  ConvArgs ca;
  ca.src[0] = KEY;   ca.dst[0] = Xk;  ca.n[0] = B_ * L_ * INK;
  ca.src[1] = QUERY; ca.dst[1] = Xq;  ca.n[1] = B_ * L_ * INK;
  ca.src[2] = VALUE; ca.dst[2] = Xv;  ca.n[2] = B_ * L_ * INK;
  ca.src[3] = W_w;   ca.dst[3] = Wb;  ca.n[3] = HID * INK;
  ca.src[4] = Wv_w;  ca.dst[4] = Wvb; ca.n[4] = HID * INK;
  ca.Wo = Wo_w;      ca.Wop = Wop;
  convert_kernel<<<dim3(2048, 6), 256, 0, stream>>>(ca);

  const float c2 = 0.12751744f;  // log2(e)/sqrt(128)
  ProjArgs pa;
  pa.X[0] = Xk;  pa.W[0] = Wb;  pa.bias[0] = W_b;  pa.scale[0] = 1.0f; pa.out[0] = Kp;
  pa.X[1] = Xq;  pa.W[1] = Wb;  pa.bias[1] = W_b;  pa.scale[1] = c2;   pa.out[1] = Qp;
  pa.X[2] = Xv;  pa.W[2] = Wvb; pa.bias[2] = Wv_b; pa.scale[2] = 1.0f; pa.out[2] = Vg;
  proj_kernel<<<dim3(64, 8, 3), 256, 0, stream>>>(pa);

  fused_attn_kernel<<<dim3(256), 512, 0, stream>>>(Kp, Qp, Vg, Hd0, Hd1);

  outproj_kernel<<<dim3(128, 4), 256, 0, stream>>>(Hd0, Hd1, Wop, Wo_b, out);
}